// Round 1
// baseline (2467.696 us; speedup 1.0000x reference)
//
#include <hip/hip_runtime.h>
#include <hip/hip_bf16.h>
#include <math.h>

#define B_SZ    2
#define LSEQ    1024
#define D_MODEL 2048
#define D_INNER 4096
#define D_STATE 16
#define DT_RANK 128
#define M_TOK   (B_SZ * LSEQ)      // 2048 token rows
#define PROJ_LD (2 * D_INNER)      // 8192

__device__ __forceinline__ float softplusf_(float x) {
    // numerically stable log1p(exp(x)) = max(x,0) + log1p(exp(-|x|))
    return fmaxf(x, 0.f) + log1pf(expf(-fabsf(x)));
}

// ---------------------------------------------------------------------------
// Generic fp32 GEMM:  C[M,N] = A[M,K] * B[N,K]^T   (both K-major / row-major)
// 128x128 tile, BK=16, 256 threads, 8x8 per thread.
// epi: 0 = none, 1 = softplus(v + bias[n])
// ---------------------------------------------------------------------------
__global__ __launch_bounds__(256, 2)
void gemm_abt_128(const float* __restrict__ A, int lda,
                  const float* __restrict__ Bm, int ldb,
                  float* __restrict__ C, int ldc,
                  const float* __restrict__ bias,
                  int M, int N, int K, int epi)
{
    __shared__ float As[16][132];   // [k][m], pad 132: 16B-aligned, banks shift by 4/k
    __shared__ float Bs[16][132];   // [k][n]
    const int t  = threadIdx.x;
    const int tx = t & 15, ty = t >> 4;
    const int bm = blockIdx.y << 7, bn = blockIdx.x << 7;

    float acc[8][8];
#pragma unroll
    for (int i = 0; i < 8; ++i)
#pragma unroll
        for (int j = 0; j < 8; ++j) acc[i][j] = 0.f;

    const int nkt = K >> 4;
    for (int kt = 0; kt < nkt; ++kt) {
        const int k0 = kt << 4;
#pragma unroll
        for (int it = 0; it < 2; ++it) {
            const int i   = t + (it << 8);
            const int row = i >> 2;          // 0..127
            const int kq  = (i & 3) << 2;    // 0,4,8,12
            const float4 av = *(const float4*)&A[(size_t)(bm + row) * lda + k0 + kq];
            As[kq + 0][row] = av.x; As[kq + 1][row] = av.y;
            As[kq + 2][row] = av.z; As[kq + 3][row] = av.w;
            const int gn = bn + row;
            float4 bv = make_float4(0.f, 0.f, 0.f, 0.f);
            if (gn < N) bv = *(const float4*)&Bm[(size_t)gn * ldb + k0 + kq];
            Bs[kq + 0][row] = bv.x; Bs[kq + 1][row] = bv.y;
            Bs[kq + 2][row] = bv.z; Bs[kq + 3][row] = bv.w;
        }
        __syncthreads();
#pragma unroll
        for (int kk = 0; kk < 16; ++kk) {
            const float4 a0 = *(const float4*)&As[kk][(ty << 2)];
            const float4 a1 = *(const float4*)&As[kk][(ty << 2) + 64];
            const float4 b0 = *(const float4*)&Bs[kk][(tx << 2)];
            const float4 b1 = *(const float4*)&Bs[kk][(tx << 2) + 64];
            const float av[8] = {a0.x, a0.y, a0.z, a0.w, a1.x, a1.y, a1.z, a1.w};
            const float bv[8] = {b0.x, b0.y, b0.z, b0.w, b1.x, b1.y, b1.z, b1.w};
#pragma unroll
            for (int i = 0; i < 8; ++i)
#pragma unroll
                for (int j = 0; j < 8; ++j)
                    acc[i][j] = fmaf(av[i], bv[j], acc[i][j]);
        }
        __syncthreads();
    }

    const int cn0 = bn + (tx << 2);
#pragma unroll
    for (int i = 0; i < 8; ++i) {
        const int gm = bm + ((i >> 2) << 6) + (ty << 2) + (i & 3);
        if (cn0 < N) {
            float v0 = acc[i][0], v1 = acc[i][1], v2 = acc[i][2], v3 = acc[i][3];
            if (epi == 1) {
                v0 = softplusf_(v0 + bias[cn0 + 0]);
                v1 = softplusf_(v1 + bias[cn0 + 1]);
                v2 = softplusf_(v2 + bias[cn0 + 2]);
                v3 = softplusf_(v3 + bias[cn0 + 3]);
            }
            *(float4*)&C[(size_t)gm * ldc + cn0] = make_float4(v0, v1, v2, v3);
        }
        if (cn0 + 64 < N) {
            float v0 = acc[i][4], v1 = acc[i][5], v2 = acc[i][6], v3 = acc[i][7];
            if (epi == 1) {
                v0 = softplusf_(v0 + bias[cn0 + 64]);
                v1 = softplusf_(v1 + bias[cn0 + 65]);
                v2 = softplusf_(v2 + bias[cn0 + 66]);
                v3 = softplusf_(v3 + bias[cn0 + 67]);
            }
            *(float4*)&C[(size_t)gm * ldc + cn0 + 64] = make_float4(v0, v1, v2, v3);
        }
    }
}

// ---------------------------------------------------------------------------
// Skinny GEMM for x_proj (N=160):  C[M,N] = A[M,K] * B[N,K]^T
// 64x16 tile, BK=16, 256 threads, 4 outputs/thread. Grid saturation > tile FLOPs.
// ---------------------------------------------------------------------------
__global__ __launch_bounds__(256, 2)
void gemm_abt_64x16(const float* __restrict__ A, int lda,
                    const float* __restrict__ Bm, int ldb,
                    float* __restrict__ C, int ldc,
                    int M, int N, int K)
{
    __shared__ float As[16][68];
    __shared__ float Bs[16][20];
    const int t  = threadIdx.x;
    const int tx = t & 15, ty = t >> 4;
    const int bm = blockIdx.y << 6, bn = blockIdx.x << 4;
    float acc[4] = {0.f, 0.f, 0.f, 0.f};
    const int nkt = K >> 4;
    for (int kt = 0; kt < nkt; ++kt) {
        const int k0 = kt << 4;
        {
            const int row = t >> 2;          // 0..63
            const int kq  = (t & 3) << 2;
            const float4 av = *(const float4*)&A[(size_t)(bm + row) * lda + k0 + kq];
            As[kq + 0][row] = av.x; As[kq + 1][row] = av.y;
            As[kq + 2][row] = av.z; As[kq + 3][row] = av.w;
        }
        if (t < 64) {
            const int row = t >> 2;          // 0..15 (n)
            const int kq  = (t & 3) << 2;
            const int gn  = bn + row;
            float4 bv = make_float4(0.f, 0.f, 0.f, 0.f);
            if (gn < N) bv = *(const float4*)&Bm[(size_t)gn * ldb + k0 + kq];
            Bs[kq + 0][row] = bv.x; Bs[kq + 1][row] = bv.y;
            Bs[kq + 2][row] = bv.z; Bs[kq + 3][row] = bv.w;
        }
        __syncthreads();
#pragma unroll
        for (int kk = 0; kk < 16; ++kk) {
            const float4 a = *(const float4*)&As[kk][ty << 2];
            const float  b = Bs[kk][tx];
            acc[0] = fmaf(a.x, b, acc[0]);
            acc[1] = fmaf(a.y, b, acc[1]);
            acc[2] = fmaf(a.z, b, acc[2]);
            acc[3] = fmaf(a.w, b, acc[3]);
        }
        __syncthreads();
    }
    const int gn = bn + tx;
    if (gn < N) {
#pragma unroll
        for (int i = 0; i < 4; ++i)
            C[(size_t)(bm + (ty << 2) + i) * ldc + gn] = acc[i];
    }
}

// ---------------------------------------------------------------------------
// Depthwise causal conv (K=4) + bias + SiLU.  Reads x = proj[:, 0:4096].
// ---------------------------------------------------------------------------
__global__ __launch_bounds__(256)
void conv_silu_k(const float* __restrict__ proj,
                 const float* __restrict__ cw,
                 const float* __restrict__ cb,
                 float* __restrict__ xt)
{
    const int d = (blockIdx.x << 8) + threadIdx.x;   // 0..4095
    const int m = blockIdx.y;                        // 0..2047 (b*L + l)
    const int l = m & (LSEQ - 1);
    const float4 w = *(const float4*)&cw[d << 2];
    const float wv[4] = {w.x, w.y, w.z, w.w};
    float acc = cb[d];
    const float* p = proj + (size_t)m * PROJ_LD + d;
#pragma unroll
    for (int j = 0; j < 4; ++j) {
        const int ls = l - 3 + j;
        if (ls >= 0) acc = fmaf(wv[j], p[(j - 3) * PROJ_LD], acc);
    }
    const float sg = 1.f / (1.f + expf(-acc));
    xt[(size_t)m * D_INNER + d] = acc * sg;
}

// ---------------------------------------------------------------------------
// Selective scan. thread = (d-group g, state s); 16 d x 16 s per block.
// dt lives in proj[:, 0:4096] (post-softplus), gate in proj[:, 4096:8192].
// Writes gated y in place over xt (read-before-write within the same wave).
// ---------------------------------------------------------------------------
__global__ __launch_bounds__(256)
void scan_k(const float* __restrict__ proj,   // dt @ [m][d], gate @ [m][4096+d], ld 8192
            float* __restrict__ xt,           // x in / y_gated out, ld 4096
            const float* __restrict__ ssm,    // [m][160]: B @ 128+s, C @ 144+s
            const float* __restrict__ Ap,     // [4096][16]
            const float* __restrict__ Dp)     // [4096]
{
    const int t = threadIdx.x;
    const int s = t & 15, g = t >> 4;
    const int d = (blockIdx.x << 4) + g;
    const int b = blockIdx.y;
    const float a  = Ap[d * D_STATE + s];
    const float Dd = Dp[d];
    float state = 0.f;
    const size_t mrow = (size_t)b * LSEQ;
    for (int l = 0; l < LSEQ; ++l) {
        const size_t m = mrow + l;
        const float dt_v = proj[m * PROJ_LD + d];
        const float x_v  = xt[m * D_INNER + d];
        const float Bv   = ssm[m * 160 + 128 + s];
        const float Cv   = ssm[m * 160 + 144 + s];
        const float dA   = __expf(dt_v * a);
        state = fmaf(state, dA, dt_v * Bv * x_v);
        float yp = state * Cv;
        yp += __shfl_xor(yp, 1);
        yp += __shfl_xor(yp, 2);
        yp += __shfl_xor(yp, 4);
        yp += __shfl_xor(yp, 8);
        if (s == 0) {
            const float gv  = proj[m * PROJ_LD + D_INNER + d];
            const float sig = 1.f / (1.f + expf(-gv));
            xt[m * D_INNER + d] = fmaf(Dd, x_v, yp) * (gv * sig);
        }
    }
}

// ---------------------------------------------------------------------------
extern "C" void kernel_launch(void* const* d_in, const int* in_sizes, int n_in,
                              void* d_out, int out_size, void* d_ws, size_t ws_size,
                              hipStream_t stream)
{
    (void)in_sizes; (void)n_in; (void)out_size; (void)ws_size;
    const float* hs  = (const float*)d_in[0];  // [2,1024,2048]
    const float* inw = (const float*)d_in[1];  // [8192,2048]
    const float* cw  = (const float*)d_in[2];  // [4096,4]
    const float* cb  = (const float*)d_in[3];  // [4096]
    const float* xw  = (const float*)d_in[4];  // [160,4096]
    const float* dtw = (const float*)d_in[5];  // [4096,128]
    const float* dtb = (const float*)d_in[6];  // [4096]
    const float* Ap  = (const float*)d_in[7];  // [4096,16]
    const float* Dp  = (const float*)d_in[8];  // [4096]
    const float* ow  = (const float*)d_in[9];  // [2048,4096]
    float* out = (float*)d_out;                // [2,1024,2048]

    float* ws   = (float*)d_ws;
    float* proj = ws;                                    // [2048][8192]  64 MB
    float* xt   = ws + (size_t)M_TOK * PROJ_LD;          // [2048][4096]  32 MB
    float* ssm  = xt + (size_t)M_TOK * D_INNER;          // [2048][160]   1.25 MB

    const dim3 blk(256);

    // 1) in_proj: proj = hs @ inw^T   [2048 x 8192], K=2048
    gemm_abt_128<<<dim3(PROJ_LD / 128, M_TOK / 128), blk, 0, stream>>>(
        hs, D_MODEL, inw, D_MODEL, proj, PROJ_LD, nullptr, M_TOK, PROJ_LD, D_MODEL, 0);

    // 2) depthwise causal conv + SiLU -> xt
    conv_silu_k<<<dim3(D_INNER / 256, M_TOK), blk, 0, stream>>>(proj, cw, cb, xt);

    // 3) x_proj: ssm = xt @ xw^T   [2048 x 160], K=4096
    gemm_abt_64x16<<<dim3(160 / 16, M_TOK / 64), blk, 0, stream>>>(
        xt, D_INNER, xw, D_INNER, ssm, 160, M_TOK, 160, D_INNER);

    // 4) dt_proj + softplus(+bias): dt -> proj[:, 0:4096] (x-half is dead now)
    gemm_abt_128<<<dim3(D_INNER / 128, M_TOK / 128), blk, 0, stream>>>(
        ssm, 160, dtw, DT_RANK, proj, PROJ_LD, dtb, M_TOK, D_INNER, DT_RANK, 1);

    // 5) selective scan + D-skip + gate  (writes y_gated over xt)
    scan_k<<<dim3(D_INNER / 16, B_SZ), blk, 0, stream>>>(proj, xt, ssm, Ap, Dp);

    // 6) out_proj: out = y @ ow^T   [2048 x 2048], K=4096
    gemm_abt_128<<<dim3(D_MODEL / 128, M_TOK / 128), blk, 0, stream>>>(
        xt, D_INNER, ow, D_INNER, out, D_MODEL, nullptr, M_TOK, D_MODEL, D_INNER, 0);
}

// Round 2
// 754.509 us; speedup vs baseline: 3.2706x; 3.2706x over previous
//
#include <hip/hip_runtime.h>
#include <hip/hip_bf16.h>
#include <math.h>

#define B_SZ    2
#define LSEQ    1024
#define D_MODEL 2048
#define D_INNER 4096
#define D_STATE 16
#define DT_RANK 128
#define M_TOK   (B_SZ * LSEQ)      // 2048 token rows
#define PROJ_LD (2 * D_INNER)      // 8192
#define NCHUNK  8
#define LCHUNK  (LSEQ / NCHUNK)    // 128

typedef __attribute__((ext_vector_type(8))) short bf16x8;
typedef __attribute__((ext_vector_type(4))) float f32x4;

__device__ __forceinline__ float softplusf_(float x) {
    return fmaxf(x, 0.f) + log1pf(expf(-fabsf(x)));
}

__device__ __forceinline__ unsigned f2bf(float f) {
    union { float f; unsigned u; } v; v.f = f;
    const unsigned u = v.u;
    return (u + 0x7fffu + ((u >> 16) & 1u)) >> 16;   // RNE, finite inputs
}

// ---------------------------------------------------------------------------
// bf16 MFMA GEMM:  C[M,N] = A[M,K](fp32) * B[N,K](fp32)^T, fp32 accumulate.
// 128x128 tile, BK=32, 256 threads (4 waves in 2x2), reg-staged fp32->bf16.
// LDS layout [row][32k] bf16, XOR swizzle byte ^= (row&3)<<4 (2-way max).
// epi: 0=none, 1=softplus(v+bias[col]).
// ---------------------------------------------------------------------------
__global__ __launch_bounds__(256, 2)
void gemm_mfma_bt(const float* __restrict__ A, int lda,
                  const float* __restrict__ B, int ldb,
                  float* __restrict__ C, int ldc,
                  const float* __restrict__ bias,
                  int M, int N, int K, int epi)
{
    __shared__ ushort As[128 * 32];
    __shared__ ushort Bs[128 * 32];
    char* Asb = (char*)As;
    char* Bsb = (char*)Bs;
    const int t    = threadIdx.x;
    const int bm   = blockIdx.y << 7, bn = blockIdx.x << 7;
    const int wave = t >> 6, lane = t & 63;
    const int wr   = (wave >> 1) << 6;    // wave row offset in tile
    const int wc   = (wave & 1) << 6;     // wave col offset in tile
    const int lr   = lane & 15, lh = lane >> 4;

    f32x4 acc[4][4];
#pragma unroll
    for (int i = 0; i < 4; ++i)
#pragma unroll
        for (int j = 0; j < 4; ++j) {
            acc[i][j][0] = 0.f; acc[i][j][1] = 0.f;
            acc[i][j][2] = 0.f; acc[i][j][3] = 0.f;
        }

#define LOADT(kt, RA, RB) do {                                          \
    const int k0_ = (kt) << 5;                                          \
    _Pragma("unroll")                                                   \
    for (int it = 0; it < 2; ++it) {                                    \
        const int idx_ = t + (it << 8);                                 \
        const int row_ = idx_ >> 2;                                     \
        const int kq_  = (idx_ & 3) << 3;                               \
        const float* pa_ = A + (size_t)(bm + row_) * lda + k0_ + kq_;   \
        RA[it][0] = *(const float4*)pa_;                                \
        RA[it][1] = *(const float4*)(pa_ + 4);                          \
        int gn_ = bn + row_; gn_ = gn_ < N ? gn_ : N - 1;               \
        const float* pb_ = B + (size_t)gn_ * ldb + k0_ + kq_;           \
        RB[it][0] = *(const float4*)pb_;                                \
        RB[it][1] = *(const float4*)(pb_ + 4);                          \
    }                                                                   \
} while (0)

#define STORET(RA, RB) do {                                             \
    _Pragma("unroll")                                                   \
    for (int it = 0; it < 2; ++it) {                                    \
        const int idx_ = t + (it << 8);                                 \
        const int row_ = idx_ >> 2;                                     \
        const int kq_  = (idx_ & 3) << 3;                               \
        const int off_ = (((row_ << 6) + (kq_ << 1))) ^ ((row_ & 3) << 4); \
        int4 pa_, pb_;                                                  \
        pa_.x = (int)(f2bf(RA[it][0].x) | (f2bf(RA[it][0].y) << 16));   \
        pa_.y = (int)(f2bf(RA[it][0].z) | (f2bf(RA[it][0].w) << 16));   \
        pa_.z = (int)(f2bf(RA[it][1].x) | (f2bf(RA[it][1].y) << 16));   \
        pa_.w = (int)(f2bf(RA[it][1].z) | (f2bf(RA[it][1].w) << 16));   \
        pb_.x = (int)(f2bf(RB[it][0].x) | (f2bf(RB[it][0].y) << 16));   \
        pb_.y = (int)(f2bf(RB[it][0].z) | (f2bf(RB[it][0].w) << 16));   \
        pb_.z = (int)(f2bf(RB[it][1].x) | (f2bf(RB[it][1].y) << 16));   \
        pb_.w = (int)(f2bf(RB[it][1].z) | (f2bf(RB[it][1].w) << 16));   \
        *(int4*)(Asb + off_) = pa_;                                     \
        *(int4*)(Bsb + off_) = pb_;                                     \
    }                                                                   \
} while (0)

#define COMPUTET do {                                                   \
    bf16x8 af_[4], bf_[4];                                              \
    _Pragma("unroll")                                                   \
    for (int mi = 0; mi < 4; ++mi) {                                    \
        const int row_ = wr + (mi << 4) + lr;                           \
        const int off_ = ((row_ << 6) + (lh << 4)) ^ ((row_ & 3) << 4); \
        af_[mi] = *(const bf16x8*)(Asb + off_);                         \
    }                                                                   \
    _Pragma("unroll")                                                   \
    for (int nj = 0; nj < 4; ++nj) {                                    \
        const int row_ = wc + (nj << 4) + lr;                           \
        const int off_ = ((row_ << 6) + (lh << 4)) ^ ((row_ & 3) << 4); \
        bf_[nj] = *(const bf16x8*)(Bsb + off_);                         \
    }                                                                   \
    _Pragma("unroll")                                                   \
    for (int mi = 0; mi < 4; ++mi)                                      \
        _Pragma("unroll")                                               \
        for (int nj = 0; nj < 4; ++nj)                                  \
            acc[mi][nj] = __builtin_amdgcn_mfma_f32_16x16x32_bf16(      \
                af_[mi], bf_[nj], acc[mi][nj], 0, 0, 0);                \
} while (0)

    float4 ra[2][2], rb[2][2], ra2[2][2], rb2[2][2];
    const int nkt = K >> 5;
    LOADT(0, ra, rb);
    for (int kt = 0; kt < nkt; kt += 2) {
        __syncthreads();
        STORET(ra, rb);
        __syncthreads();
        if (kt + 1 < nkt) LOADT(kt + 1, ra2, rb2);
        COMPUTET;
        if (kt + 1 < nkt) {
            __syncthreads();
            STORET(ra2, rb2);
            __syncthreads();
            if (kt + 2 < nkt) LOADT(kt + 2, ra, rb);
            COMPUTET;
        }
    }

#pragma unroll
    for (int mi = 0; mi < 4; ++mi) {
#pragma unroll
        for (int nj = 0; nj < 4; ++nj) {
            const int col  = bn + wc + (nj << 4) + lr;
            const int row0 = bm + wr + (mi << 4) + (lh << 2);
            if (col < N) {
#pragma unroll
                for (int r = 0; r < 4; ++r) {
                    float v = acc[mi][nj][r];
                    if (epi == 1) v = softplusf_(v + bias[col]);
                    C[(size_t)(row0 + r) * ldc + col] = v;
                }
            }
        }
    }
#undef LOADT
#undef STORET
#undef COMPUTET
}

// ---------------------------------------------------------------------------
// Depthwise causal conv (K=4) + bias + SiLU.  Reads x = proj[:, 0:4096].
// ---------------------------------------------------------------------------
__global__ __launch_bounds__(256)
void conv_silu_k(const float* __restrict__ proj,
                 const float* __restrict__ cw,
                 const float* __restrict__ cb,
                 float* __restrict__ xt)
{
    const int d = (blockIdx.x << 8) + threadIdx.x;   // 0..4095
    const int m = blockIdx.y;                        // 0..2047
    const int l = m & (LSEQ - 1);
    const float4 w = *(const float4*)&cw[d << 2];
    const float wv[4] = {w.x, w.y, w.z, w.w};
    float acc = cb[d];
    const float* p = proj + (size_t)m * PROJ_LD + d;
#pragma unroll
    for (int j = 0; j < 4; ++j) {
        const int ls = l - 3 + j;
        if (ls >= 0) acc = fmaf(wv[j], p[(j - 3) * PROJ_LD], acc);
    }
    const float sg = 1.f / (1.f + expf(-acc));
    xt[(size_t)m * D_INNER + d] = acc * sg;
}

// ---------------------------------------------------------------------------
// Chunked selective scan, 3 passes. thread=(b,d,s) within chunk c.
// P/Q layout: [b][d][c][s]  (c=NCHUNK chunks of LCHUNK steps)
// ---------------------------------------------------------------------------
__global__ __launch_bounds__(256)
void scan_pass1(const float* __restrict__ proj,   // dt @ [m][d], ld 8192
                const float* __restrict__ xt,     // x, ld 4096
                const float* __restrict__ ssm,    // [m][160], B @ 128+s
                const float* __restrict__ Ap,     // [4096][16]
                float* __restrict__ Pc, float* __restrict__ Qc)
{
    const int t = threadIdx.x;
    const int s = t & 15, g = t >> 4;
    const int d = (blockIdx.x << 4) + g;
    const int c = blockIdx.y, b = blockIdx.z;
    const float a = Ap[d * D_STATE + s];
    float P = 1.f, q = 0.f;
    const size_t m0 = (size_t)b * LSEQ + c * LCHUNK;
    for (int l = 0; l < LCHUNK; ++l) {
        const size_t m = m0 + l;
        const float dt_v = proj[m * PROJ_LD + d];
        const float x_v  = xt[m * D_INNER + d];
        const float Bv   = ssm[m * 160 + 128 + s];
        const float dA   = __expf(dt_v * a);
        q = fmaf(q, dA, dt_v * Bv * x_v);
        P *= dA;
    }
    const size_t o = (((size_t)b * D_INNER + d) * NCHUNK + c) * D_STATE + s;
    Pc[o] = P; Qc[o] = q;
}

__global__ __launch_bounds__(256)
void scan_pass2(const float* __restrict__ Pc, float* __restrict__ Qc)
{
    const size_t i = (size_t)blockIdx.x * 256 + threadIdx.x;  // (b*4096+d)*16+s
    const size_t base = (i >> 4) * (NCHUNK * D_STATE) + (i & 15);
    float P[NCHUNK], q[NCHUNK];
#pragma unroll
    for (int c = 0; c < NCHUNK; ++c) {
        P[c] = Pc[base + c * D_STATE];
        q[c] = Qc[base + c * D_STATE];
    }
    float st = 0.f;
#pragma unroll
    for (int c = 0; c < NCHUNK; ++c) {
        Qc[base + c * D_STATE] = st;        // state entering chunk c
        st = fmaf(st, P[c], q[c]);
    }
}

__global__ __launch_bounds__(256)
void scan_pass3(const float* __restrict__ proj,   // dt @ [m][d], gate @ [m][4096+d]
                float* __restrict__ xt,           // x in / y_gated out (in place)
                const float* __restrict__ ssm,
                const float* __restrict__ Ap,
                const float* __restrict__ Qc,     // initial states per chunk
                const float* __restrict__ Dp)
{
    const int t = threadIdx.x;
    const int s = t & 15, g = t >> 4;
    const int d = (blockIdx.x << 4) + g;
    const int c = blockIdx.y, b = blockIdx.z;
    const float a  = Ap[d * D_STATE + s];
    const float Dd = Dp[d];
    float state = Qc[(((size_t)b * D_INNER + d) * NCHUNK + c) * D_STATE + s];
    const size_t m0 = (size_t)b * LSEQ + c * LCHUNK;
    for (int l = 0; l < LCHUNK; ++l) {
        const size_t m = m0 + l;
        const float dt_v = proj[m * PROJ_LD + d];
        const float x_v  = xt[m * D_INNER + d];
        const float Bv   = ssm[m * 160 + 128 + s];
        const float Cv   = ssm[m * 160 + 144 + s];
        const float dA   = __expf(dt_v * a);
        state = fmaf(state, dA, dt_v * Bv * x_v);
        float yp = state * Cv;
        yp += __shfl_xor(yp, 1);
        yp += __shfl_xor(yp, 2);
        yp += __shfl_xor(yp, 4);
        yp += __shfl_xor(yp, 8);
        if (s == 0) {
            const float gv  = proj[m * PROJ_LD + D_INNER + d];
            const float sig = 1.f / (1.f + expf(-gv));
            xt[m * D_INNER + d] = fmaf(Dd, x_v, yp) * (gv * sig);
        }
    }
}

// ---------------------------------------------------------------------------
extern "C" void kernel_launch(void* const* d_in, const int* in_sizes, int n_in,
                              void* d_out, int out_size, void* d_ws, size_t ws_size,
                              hipStream_t stream)
{
    (void)in_sizes; (void)n_in; (void)out_size; (void)ws_size;
    const float* hs  = (const float*)d_in[0];  // [2,1024,2048]
    const float* inw = (const float*)d_in[1];  // [8192,2048]
    const float* cw  = (const float*)d_in[2];  // [4096,4]
    const float* cb  = (const float*)d_in[3];  // [4096]
    const float* xw  = (const float*)d_in[4];  // [160,4096]
    const float* dtw = (const float*)d_in[5];  // [4096,128]
    const float* dtb = (const float*)d_in[6];  // [4096]
    const float* Ap  = (const float*)d_in[7];  // [4096,16]
    const float* Dp  = (const float*)d_in[8];  // [4096]
    const float* ow  = (const float*)d_in[9];  // [2048,4096]
    float* out = (float*)d_out;                // [2,1024,2048]

    float* ws   = (float*)d_ws;
    float* proj = ws;                                    // [2048][8192]  64 MB
    float* xt   = proj + (size_t)M_TOK * PROJ_LD;        // [2048][4096]  32 MB
    float* ssm  = xt + (size_t)M_TOK * D_INNER;          // [2048][160]   1.25 MB
    float* Pc   = ssm + (size_t)M_TOK * 160;             // [2][4096][8][16] 4.2 MB
    float* Qc   = Pc + (size_t)B_SZ * D_INNER * NCHUNK * D_STATE; // 4.2 MB

    const dim3 blk(256);

    // 1) in_proj: proj = hs @ inw^T   [2048 x 8192], K=2048
    gemm_mfma_bt<<<dim3(PROJ_LD / 128, M_TOK / 128), blk, 0, stream>>>(
        hs, D_MODEL, inw, D_MODEL, proj, PROJ_LD, nullptr, M_TOK, PROJ_LD, D_MODEL, 0);

    // 2) depthwise causal conv + SiLU -> xt
    conv_silu_k<<<dim3(D_INNER / 256, M_TOK), blk, 0, stream>>>(proj, cw, cb, xt);

    // 3) x_proj: ssm = xt @ xw^T   [2048 x 160], K=4096
    gemm_mfma_bt<<<dim3(2, M_TOK / 128), blk, 0, stream>>>(
        xt, D_INNER, xw, D_INNER, ssm, 160, nullptr, M_TOK, 160, D_INNER, 0);

    // 4) dt_proj + softplus(+bias): dt -> proj[:, 0:4096]
    gemm_mfma_bt<<<dim3(D_INNER / 128, M_TOK / 128), blk, 0, stream>>>(
        ssm, 160, dtw, DT_RANK, proj, PROJ_LD, dtb, M_TOK, D_INNER, DT_RANK, 1);

    // 5) chunked selective scan + D-skip + gate (y_gated over xt in place)
    scan_pass1<<<dim3(D_INNER / 16, NCHUNK, B_SZ), blk, 0, stream>>>(
        proj, xt, ssm, Ap, Pc, Qc);
    scan_pass2<<<dim3((B_SZ * D_INNER * D_STATE) / 256), blk, 0, stream>>>(Pc, Qc);
    scan_pass3<<<dim3(D_INNER / 16, NCHUNK, B_SZ), blk, 0, stream>>>(
        proj, xt, ssm, Ap, Qc, Dp);

    // 6) out_proj: out = y @ ow^T   [2048 x 2048], K=4096
    gemm_mfma_bt<<<dim3(D_MODEL / 128, M_TOK / 128), blk, 0, stream>>>(
        xt, D_INNER, ow, D_INNER, out, D_MODEL, nullptr, M_TOK, D_MODEL, D_INNER, 0);
}

// Round 3
// 371.534 us; speedup vs baseline: 6.6419x; 2.0308x over previous
//
#include <hip/hip_runtime.h>
#include <hip/hip_bf16.h>
#include <math.h>

#define B_SZ    2
#define LSEQ    1024
#define D_MODEL 2048
#define D_INNER 4096
#define D_STATE 16
#define DT_RANK 128
#define M_TOK   (B_SZ * LSEQ)      // 2048 token rows
#define NCHUNK  16
#define LCHUNK  (LSEQ / NCHUNK)    // 64

typedef __attribute__((ext_vector_type(8))) short bf16x8;
typedef __attribute__((ext_vector_type(4))) float f32x4;

__device__ __forceinline__ float softplusf_(float x) {
    return fmaxf(x, 0.f) + log1pf(expf(-fabsf(x)));
}
__device__ __forceinline__ unsigned f2bf(float f) {
    union { float f; unsigned u; } v; v.f = f;
    const unsigned u = v.u;
    return (u + 0x7fffu + ((u >> 16) & 1u)) >> 16;   // RNE, finite inputs
}
__device__ __forceinline__ float bf2f(unsigned u) {
    union { unsigned u; float f; } v; v.u = u << 16; return v.f;
}
__device__ __forceinline__ void gload16(const void* g, void* lds) {
    __builtin_amdgcn_global_load_lds(
        (const __attribute__((address_space(1))) void*)g,
        (__attribute__((address_space(3))) void*)lds, 16, 0, 0);
}

// ---------------------------------------------------------------------------
// bf16 MFMA GEMM, m97-style: C[M,N] = A[M,K](bf16) * B[N,K](bf16)^T, fp32 acc.
// 128x128 tile, BK=64, 256 thr (4 waves 2x2), global_load_lds staging with
// inverse-swizzled SOURCE + XOR-swizzled ds_read (chunk ^= row&7, 2-way max).
// Split-K via gridDim.z (C += z*zstride, K sliced). epi: 0=f32, 1=softplus+bias,
// 4=bf16 store.
// ---------------------------------------------------------------------------
__global__ __launch_bounds__(256, 3)
void gemm_bf16_bt(const ushort* __restrict__ A, int lda,
                  const ushort* __restrict__ B, int ldb,
                  void* __restrict__ Cv, int ldc,
                  const float* __restrict__ bias,
                  int M, int N, int K, int epi, size_t zstride)
{
    __shared__ ushort As[128 * 64];
    __shared__ ushort Bs[128 * 64];
    const int t    = threadIdx.x;
    const int bm   = blockIdx.y << 7, bn = blockIdx.x << 7;
    const int wave = t >> 6, lane = t & 63;
    const int wr   = (wave >> 1) << 6, wc = (wave & 1) << 6;
    const int lr   = lane & 15, lh = lane >> 4;
    const int kper  = K / gridDim.z;
    const int kbase = blockIdx.z * kper;
    const int nkt   = kper >> 6;

    // staging pointers: flat = t + it*256; row = flat>>3; j = flat&7; jj = j^(row&7)
    const ushort* ga[4]; const ushort* gb[4];
    ushort* la[4]; ushort* lb[4];
#pragma unroll
    for (int it = 0; it < 4; ++it) {
        const int flat = t + (it << 8);
        const int row  = flat >> 3, j = flat & 7;
        const int jj   = j ^ (row & 7);
        ga[it] = A + (size_t)(bm + row) * lda + kbase + jj * 8;
        int gn = bn + row; gn = gn < N ? gn : N - 1;
        gb[it] = B + (size_t)gn * ldb + kbase + jj * 8;
        const int ci = (it << 2) + wave;          // wave-uniform dest chunk
        la[it] = As + ci * 512;
        lb[it] = Bs + ci * 512;
    }

    f32x4 acc[4][4];
#pragma unroll
    for (int i = 0; i < 4; ++i)
#pragma unroll
        for (int j = 0; j < 4; ++j) {
            acc[i][j][0] = 0.f; acc[i][j][1] = 0.f;
            acc[i][j][2] = 0.f; acc[i][j][3] = 0.f;
        }

    for (int kt = 0; kt < nkt; ++kt) {
        if (kt) __syncthreads();
#pragma unroll
        for (int it = 0; it < 4; ++it) {
            gload16(ga[it], la[it]);
            gload16(gb[it], lb[it]);
            ga[it] += 64; gb[it] += 64;
        }
        asm volatile("s_waitcnt vmcnt(0)" ::: "memory");
        __syncthreads();
#pragma unroll
        for (int kk = 0; kk < 2; ++kk) {
            bf16x8 af[4], bf[4];
#pragma unroll
            for (int mi = 0; mi < 4; ++mi) {
                const int row = wr + (mi << 4) + lr;
                const int ch  = ((kk << 2) + lh) ^ (row & 7);
                af[mi] = *(const bf16x8*)((const char*)As + row * 128 + (ch << 4));
            }
#pragma unroll
            for (int nj = 0; nj < 4; ++nj) {
                const int row = wc + (nj << 4) + lr;
                const int ch  = ((kk << 2) + lh) ^ (row & 7);
                bf[nj] = *(const bf16x8*)((const char*)Bs + row * 128 + (ch << 4));
            }
#pragma unroll
            for (int mi = 0; mi < 4; ++mi)
#pragma unroll
                for (int nj = 0; nj < 4; ++nj)
                    acc[mi][nj] = __builtin_amdgcn_mfma_f32_16x16x32_bf16(
                        af[mi], bf[nj], acc[mi][nj], 0, 0, 0);
        }
    }

    float*  C  = (float*)Cv + (size_t)blockIdx.z * zstride;
    ushort* Cb = (ushort*)Cv;
#pragma unroll
    for (int mi = 0; mi < 4; ++mi) {
#pragma unroll
        for (int nj = 0; nj < 4; ++nj) {
            const int col  = bn + wc + (nj << 4) + lr;
            const int row0 = bm + wr + (mi << 4) + (lh << 2);
            if (col < N) {
#pragma unroll
                for (int r = 0; r < 4; ++r) {
                    const float v = acc[mi][nj][r];
                    if (epi == 0)      C[(size_t)(row0 + r) * ldc + col] = v;
                    else if (epi == 1) C[(size_t)(row0 + r) * ldc + col] = softplusf_(v + bias[col]);
                    else               Cb[(size_t)(row0 + r) * ldc + col] = (ushort)f2bf(v);
                }
            }
        }
    }
}

// ---------------------------------------------------------------------------
__global__ __launch_bounds__(256)
void cvt_bf16(const float* __restrict__ in, ushort* __restrict__ out, int n8)
{
    for (int i = blockIdx.x * 256 + threadIdx.x; i < n8; i += gridDim.x * 256) {
        const float4 v0 = ((const float4*)in)[i * 2];
        const float4 v1 = ((const float4*)in)[i * 2 + 1];
        int4 p;
        p.x = (int)(f2bf(v0.x) | (f2bf(v0.y) << 16));
        p.y = (int)(f2bf(v0.z) | (f2bf(v0.w) << 16));
        p.z = (int)(f2bf(v1.x) | (f2bf(v1.y) << 16));
        p.w = (int)(f2bf(v1.z) | (f2bf(v1.w) << 16));
        ((int4*)out)[i] = p;
    }
}

// ---------------------------------------------------------------------------
// Depthwise causal conv (K=4) + bias + SiLU. px f32 [M][4096] -> xt bf16.
// ---------------------------------------------------------------------------
__global__ __launch_bounds__(256)
void conv_silu_k(const float* __restrict__ px,
                 const float* __restrict__ cw,
                 const float* __restrict__ cb,
                 ushort* __restrict__ xb)
{
    const int d = (blockIdx.x << 8) + threadIdx.x;
    const int m = blockIdx.y;
    const int l = m & (LSEQ - 1);
    const float4 w = *(const float4*)&cw[d << 2];
    const float wv[4] = {w.x, w.y, w.z, w.w};
    float acc = cb[d];
#pragma unroll
    for (int j = 0; j < 4; ++j) {
        const int ls = l - 3 + j;
        if (ls >= 0) acc = fmaf(wv[j], px[(size_t)(m - 3 + j) * D_INNER + d], acc);
    }
    const float sg = 1.f / (1.f + expf(-acc));
    xb[(size_t)m * D_INNER + d] = (ushort)f2bf(acc * sg);
}

// ---------------------------------------------------------------------------
__global__ __launch_bounds__(256)
void reduce_ssm(const float* __restrict__ part,
                float* __restrict__ ssmf, ushort* __restrict__ ssmb)
{
    const int i = blockIdx.x * 256 + threadIdx.x;   // < 2048*160
    float v = 0.f;
#pragma unroll
    for (int z = 0; z < 8; ++z) v += part[(size_t)z * (M_TOK * 160) + i];
    ssmf[i] = v;
    ssmb[i] = (ushort)f2bf(v);
}

// ---------------------------------------------------------------------------
// Chunked selective scan: thread owns (b, d, chunk), 16 states in VGPRs.
// ---------------------------------------------------------------------------
__global__ __launch_bounds__(256)
void scan_pass1(const float* __restrict__ dtp,    // px: dt f32 [M][4096]
                const ushort* __restrict__ xb,    // x bf16 [M][4096]
                const float* __restrict__ ssm,    // [M][160], B @ 128+s
                const float* __restrict__ Ap,     // [4096][16]
                float* __restrict__ Pc, float* __restrict__ Qc)
{
    const int d = (blockIdx.x << 8) + threadIdx.x;
    const int c = blockIdx.y, b = blockIdx.z;
    float a[16];
    *(float4*)&a[0]  = *(const float4*)&Ap[d * 16];
    *(float4*)&a[4]  = *(const float4*)&Ap[d * 16 + 4];
    *(float4*)&a[8]  = *(const float4*)&Ap[d * 16 + 8];
    *(float4*)&a[12] = *(const float4*)&Ap[d * 16 + 12];
    float q[16];
#pragma unroll
    for (int s = 0; s < 16; ++s) q[s] = 0.f;
    float dtsum = 0.f;
    const size_t m0 = (size_t)b * LSEQ + (size_t)c * LCHUNK;
#pragma unroll 2
    for (int l = 0; l < LCHUNK; ++l) {
        const size_t m = m0 + l;
        const float dt = dtp[m * D_INNER + d];
        const float xv = bf2f(xb[m * D_INNER + d]);
        const float4 B0 = *(const float4*)&ssm[m * 160 + 128];
        const float4 B1 = *(const float4*)&ssm[m * 160 + 132];
        const float4 B2 = *(const float4*)&ssm[m * 160 + 136];
        const float4 B3 = *(const float4*)&ssm[m * 160 + 140];
        const float Bv[16] = {B0.x,B0.y,B0.z,B0.w, B1.x,B1.y,B1.z,B1.w,
                              B2.x,B2.y,B2.z,B2.w, B3.x,B3.y,B3.z,B3.w};
        const float t1 = dt * xv;
#pragma unroll
        for (int s = 0; s < 16; ++s) {
            const float dA = __expf(dt * a[s]);
            q[s] = fmaf(q[s], dA, t1 * Bv[s]);
        }
        dtsum += dt;
    }
    const size_t o = (((size_t)b * D_INNER + d) * NCHUNK + c) * D_STATE;
    float P[16];
#pragma unroll
    for (int s = 0; s < 16; ++s) P[s] = __expf(a[s] * dtsum);
#pragma unroll
    for (int s4 = 0; s4 < 4; ++s4) {
        *(float4*)&Pc[o + s4 * 4] = make_float4(P[s4*4], P[s4*4+1], P[s4*4+2], P[s4*4+3]);
        *(float4*)&Qc[o + s4 * 4] = make_float4(q[s4*4], q[s4*4+1], q[s4*4+2], q[s4*4+3]);
    }
}

__global__ __launch_bounds__(256)
void scan_pass2(const float* __restrict__ Pc, float* __restrict__ Qc)
{
    const int i = blockIdx.x * 256 + threadIdx.x;   // (b*4096+d)*16+s
    const size_t base = (size_t)(i >> 4) * (NCHUNK * D_STATE) + (i & 15);
    float st = 0.f;
#pragma unroll
    for (int c = 0; c < NCHUNK; ++c) {
        const float P = Pc[base + c * D_STATE];
        const float q = Qc[base + c * D_STATE];
        Qc[base + c * D_STATE] = st;    // state entering chunk c
        st = fmaf(st, P, q);
    }
}

__global__ __launch_bounds__(256)
void scan_pass3(const float* __restrict__ dtp,    // dt f32
                ushort* __restrict__ xb,          // x bf16 in / y bf16 out
                const ushort* __restrict__ gb,    // gate bf16
                const float* __restrict__ ssm,
                const float* __restrict__ Ap,
                const float* __restrict__ Qc,
                const float* __restrict__ Dp)
{
    const int d = (blockIdx.x << 8) + threadIdx.x;
    const int c = blockIdx.y, b = blockIdx.z;
    float a[16], st[16];
    *(float4*)&a[0]  = *(const float4*)&Ap[d * 16];
    *(float4*)&a[4]  = *(const float4*)&Ap[d * 16 + 4];
    *(float4*)&a[8]  = *(const float4*)&Ap[d * 16 + 8];
    *(float4*)&a[12] = *(const float4*)&Ap[d * 16 + 12];
    const size_t qo = (((size_t)b * D_INNER + d) * NCHUNK + c) * D_STATE;
    *(float4*)&st[0]  = *(const float4*)&Qc[qo];
    *(float4*)&st[4]  = *(const float4*)&Qc[qo + 4];
    *(float4*)&st[8]  = *(const float4*)&Qc[qo + 8];
    *(float4*)&st[12] = *(const float4*)&Qc[qo + 12];
    const float Dd = Dp[d];
    const size_t m0 = (size_t)b * LSEQ + (size_t)c * LCHUNK;
#pragma unroll 2
    for (int l = 0; l < LCHUNK; ++l) {
        const size_t m = m0 + l;
        const float dt = dtp[m * D_INNER + d];
        const float xv = bf2f(xb[m * D_INNER + d]);
        const float gv = bf2f(gb[m * D_INNER + d]);
        const float4 B0 = *(const float4*)&ssm[m * 160 + 128];
        const float4 B1 = *(const float4*)&ssm[m * 160 + 132];
        const float4 B2 = *(const float4*)&ssm[m * 160 + 136];
        const float4 B3 = *(const float4*)&ssm[m * 160 + 140];
        const float4 C0 = *(const float4*)&ssm[m * 160 + 144];
        const float4 C1 = *(const float4*)&ssm[m * 160 + 148];
        const float4 C2 = *(const float4*)&ssm[m * 160 + 152];
        const float4 C3 = *(const float4*)&ssm[m * 160 + 156];
        const float Bv[16] = {B0.x,B0.y,B0.z,B0.w, B1.x,B1.y,B1.z,B1.w,
                              B2.x,B2.y,B2.z,B2.w, B3.x,B3.y,B3.z,B3.w};
        const float Cv[16] = {C0.x,C0.y,C0.z,C0.w, C1.x,C1.y,C1.z,C1.w,
                              C2.x,C2.y,C2.z,C2.w, C3.x,C3.y,C3.z,C3.w};
        const float t1 = dt * xv;
        float y = 0.f;
#pragma unroll
        for (int s = 0; s < 16; ++s) {
            const float dA = __expf(dt * a[s]);
            st[s] = fmaf(st[s], dA, t1 * Bv[s]);
            y = fmaf(st[s], Cv[s], y);
        }
        const float yg  = fmaf(Dd, xv, y);
        const float sig = 1.f / (1.f + expf(-gv));
        xb[m * D_INNER + d] = (ushort)f2bf(yg * (gv * sig));
    }
}

// ---------------------------------------------------------------------------
extern "C" void kernel_launch(void* const* d_in, const int* in_sizes, int n_in,
                              void* d_out, int out_size, void* d_ws, size_t ws_size,
                              hipStream_t stream)
{
    (void)in_sizes; (void)n_in; (void)out_size; (void)ws_size;
    const float* hs  = (const float*)d_in[0];  // [2048,2048]
    const float* inw = (const float*)d_in[1];  // [8192,2048]
    const float* cw  = (const float*)d_in[2];  // [4096,4]
    const float* cb  = (const float*)d_in[3];  // [4096]
    const float* xw  = (const float*)d_in[4];  // [160,4096]
    const float* dtw = (const float*)d_in[5];  // [4096,128]
    const float* dtb = (const float*)d_in[6];  // [4096]
    const float* Ap  = (const float*)d_in[7];  // [4096,16]
    const float* Dp  = (const float*)d_in[8];  // [4096]
    const float* ow  = (const float*)d_in[9];  // [2048,4096]
    float* out = (float*)d_out;                // [2048,2048]

    // workspace layout (f32 units), total 26,247,168 f32 = 105.0 MB
    float*  ws   = (float*)d_ws;
    float*  px   = ws;                                   // 8,388,608  (x f32, later dt)
    ushort* pg   = (ushort*)(ws + 8388608);              // gate bf16  (4,194,304 f32)
    ushort* xtb  = (ushort*)(ws + 12582912);             // x bf16, later y bf16
    float*  ssmf = ws + 16777216;                        // 327,680
    ushort* ssmb = (ushort*)(ws + 17104896);             // 163,840 f32 worth
    ushort* wU   = (ushort*)(ws + 17268736);             // 4,194,304 f32 (inw half / ow)
    ushort* xwb  = (ushort*)(ws + 21463040);             // 327,680
    ushort* dtwb = (ushort*)(ws + 21790720);             // 262,144
    float*  U2   = ws + 22052864;                        // 4,194,304 union:
    ushort* hsb  = (ushort*)U2;                          //   hs bf16 (2,097,152 f32)
    float*  part = U2;                                   //   x_proj partials (2,621,440)
    float*  Pc   = U2;                                   //   Pc (2,097,152)
    float*  Qc   = U2 + 2097152;                         //   Qc (2,097,152)

    const dim3 blk(256);

    // weight/activation conversions
    cvt_bf16<<<dim3(1280), blk, 0, stream>>>(hs, hsb, 524288);
    cvt_bf16<<<dim3(1280), blk, 0, stream>>>(xw, xwb, 81920);
    cvt_bf16<<<dim3(1280), blk, 0, stream>>>(dtw, dtwb, 65536);

    // in_proj half 1 (x): px = hs @ inw[0:4096]^T
    cvt_bf16<<<dim3(1280), blk, 0, stream>>>(inw, wU, 1048576);
    gemm_bf16_bt<<<dim3(32, 16, 1), blk, 0, stream>>>(
        hsb, D_MODEL, wU, D_MODEL, px, D_INNER, nullptr,
        M_TOK, D_INNER, D_MODEL, 0, 0);

    // in_proj half 2 (gate, bf16 out): pg = hs @ inw[4096:8192]^T
    cvt_bf16<<<dim3(1280), blk, 0, stream>>>(inw + (size_t)D_INNER * D_MODEL, wU, 1048576);
    gemm_bf16_bt<<<dim3(32, 16, 1), blk, 0, stream>>>(
        hsb, D_MODEL, wU, D_MODEL, pg, D_INNER, nullptr,
        M_TOK, D_INNER, D_MODEL, 4, 0);

    // ow conversion (wU free after gate GEMM)
    cvt_bf16<<<dim3(1280), blk, 0, stream>>>(ow, wU, 1048576);

    // conv + SiLU -> x bf16
    conv_silu_k<<<dim3(16, M_TOK), blk, 0, stream>>>(px, cw, cb, xtb);

    // x_proj split-K x8: part[z] = xtb @ xwb^T (K slice)
    gemm_bf16_bt<<<dim3(2, 16, 8), blk, 0, stream>>>(
        xtb, D_INNER, xwb, D_INNER, part, 160, nullptr,
        M_TOK, 160, D_INNER, 0, (size_t)M_TOK * 160);
    reduce_ssm<<<dim3(1280), blk, 0, stream>>>(part, ssmf, ssmb);

    // dt_proj + softplus(+bias) -> px (dt, f32)
    gemm_bf16_bt<<<dim3(32, 16, 1), blk, 0, stream>>>(
        ssmb, 160, dtwb, DT_RANK, px, D_INNER, dtb,
        M_TOK, D_INNER, DT_RANK, 1, 0);

    // chunked selective scan (+ D-skip + gate), y bf16 over xtb
    scan_pass1<<<dim3(16, NCHUNK, B_SZ), blk, 0, stream>>>(px, xtb, ssmf, Ap, Pc, Qc);
    scan_pass2<<<dim3((B_SZ * D_INNER * D_STATE) / 256), blk, 0, stream>>>(Pc, Qc);
    scan_pass3<<<dim3(16, NCHUNK, B_SZ), blk, 0, stream>>>(px, xtb, pg, ssmf, Ap, Qc, Dp);

    // out_proj: out = y @ ow^T
    gemm_bf16_bt<<<dim3(16, 16, 1), blk, 0, stream>>>(
        xtb, D_INNER, wU, D_INNER, out, D_MODEL, nullptr,
        M_TOK, D_MODEL, D_INNER, 0, 0);
}

// Round 6
// 351.708 us; speedup vs baseline: 7.0163x; 1.0564x over previous
//
#include <hip/hip_runtime.h>
#include <hip/hip_bf16.h>
#include <math.h>

#define B_SZ    2
#define LSEQ    1024
#define D_MODEL 2048
#define D_INNER 4096
#define D_STATE 16
#define DT_RANK 128
#define M_TOK   (B_SZ * LSEQ)      // 2048 token rows
#define NCHUNK  16
#define LCHUNK  (LSEQ / NCHUNK)    // 64

typedef __attribute__((ext_vector_type(8))) short bf16x8;
typedef __attribute__((ext_vector_type(4))) float f32x4;

__device__ __forceinline__ float softplusf_(float x) {
    return fmaxf(x, 0.f) + log1pf(expf(-fabsf(x)));
}
__device__ __forceinline__ unsigned f2bf(float f) {
    union { float f; unsigned u; } v; v.f = f;
    const unsigned u = v.u;
    return (u + 0x7fffu + ((u >> 16) & 1u)) >> 16;   // RNE, finite inputs
}
__device__ __forceinline__ float bf2f(unsigned u) {
    union { unsigned u; float f; } v; v.u = u << 16; return v.f;
}
__device__ __forceinline__ void gload16(const void* g, void* lds) {
    __builtin_amdgcn_global_load_lds(
        (const __attribute__((address_space(1))) void*)g,
        (__attribute__((address_space(3))) void*)lds, 16, 0, 0);
}

// ---------------------------------------------------------------------------
// bf16 MFMA GEMM: C[M,N] = A[M,K](bf16) * B[N,K](bf16)^T, fp32 acc.
// 128x128 tile, BK=64, 256 thr (4 waves 2x2). Double-buffered LDS with
// counted vmcnt(8) + raw s_barrier (prefetch loads stay in flight across
// barriers). Race ledger: a wave reaches the trailing s_barrier only after
// its ds_reads were consumed (compiler lgkmcnt before MFMA), so the next
// STAGE can't clobber live reads; vmcnt retires in issue order (m135), so
// vmcnt(8) == previous tile's 8 loads complete.
// LDS: linear dest (global_load_lds), inverse-swizzled SOURCE + swizzled
// ds_read (chunk ^= row&7) -> measured 0 bank-conflict counts (round 3).
// Split-K via gridDim.z (C += z*zstride).
// epi: 0 = f32 store; 1 = softplus(v+bias[col]) -> bf16; 5 = dual bf16
// (col<4096 -> Cv bf16 ld 4096, col>=4096 -> Cv2 bf16 ld 4096).
// ---------------------------------------------------------------------------
__global__ __launch_bounds__(256, 2)
void gemm_bf16_bt(const ushort* __restrict__ A, int lda,
                  const ushort* __restrict__ B, int ldb,
                  void* __restrict__ Cv, int ldc,
                  void* __restrict__ Cv2,
                  const float* __restrict__ bias,
                  int M, int N, int K, int epi, size_t zstride)
{
    __shared__ ushort As[2][128 * 64];
    __shared__ ushort Bs[2][128 * 64];
    const int t    = threadIdx.x;
    const int bm   = blockIdx.y << 7, bn = blockIdx.x << 7;
    const int wave = t >> 6, lane = t & 63;
    const int wr   = (wave >> 1) << 6, wc = (wave & 1) << 6;
    const int lr   = lane & 15, lh = lane >> 4;
    const int kper  = K / gridDim.z;
    const int kbase = blockIdx.z * kper;
    const int nkt   = kper >> 6;

    // staging: flat = t + it*256; row = flat>>3; j = flat&7; src chunk jj = j^(row&7)
    const ushort* ga[4]; const ushort* gb[4];
    int ci[4];
#pragma unroll
    for (int it = 0; it < 4; ++it) {
        const int flat = t + (it << 8);
        const int row  = flat >> 3, j = flat & 7;
        const int jj   = j ^ (row & 7);
        ga[it] = A + (size_t)(bm + row) * lda + kbase + jj * 8;
        int gn = bn + row; gn = gn < N ? gn : N - 1;
        gb[it] = B + (size_t)gn * ldb + kbase + jj * 8;
        ci[it] = (it << 2) + wave;            // wave-uniform dest chunk
    }

#define STAGE(bsel) do {                                                \
    _Pragma("unroll")                                                   \
    for (int it = 0; it < 4; ++it) {                                    \
        gload16(ga[it], &As[bsel][ci[it] * 512]);                       \
        gload16(gb[it], &Bs[bsel][ci[it] * 512]);                       \
        ga[it] += 64; gb[it] += 64;                                     \
    }                                                                   \
} while (0)

    f32x4 acc[4][4];
#pragma unroll
    for (int i = 0; i < 4; ++i)
#pragma unroll
        for (int j = 0; j < 4; ++j) {
            acc[i][j][0] = 0.f; acc[i][j][1] = 0.f;
            acc[i][j][2] = 0.f; acc[i][j][3] = 0.f;
        }

    STAGE(0);
    for (int kt = 0; kt < nkt; ++kt) {
        const int cur = kt & 1;
        if (kt + 1 < nkt) {
            STAGE(cur ^ 1);
            asm volatile("s_waitcnt vmcnt(8)" ::: "memory");
        } else {
            asm volatile("s_waitcnt vmcnt(0)" ::: "memory");
        }
        __builtin_amdgcn_s_barrier();          // tile kt staged by all waves
        __builtin_amdgcn_sched_barrier(0);
        const char* Ab = (const char*)As[cur];
        const char* Bb = (const char*)Bs[cur];
#pragma unroll
        for (int kk = 0; kk < 2; ++kk) {
            bf16x8 af[4], bf[4];
#pragma unroll
            for (int mi = 0; mi < 4; ++mi) {
                const int row = wr + (mi << 4) + lr;
                const int ch  = ((kk << 2) + lh) ^ (row & 7);
                af[mi] = *(const bf16x8*)(Ab + row * 128 + (ch << 4));
            }
#pragma unroll
            for (int nj = 0; nj < 4; ++nj) {
                const int row = wc + (nj << 4) + lr;
                const int ch  = ((kk << 2) + lh) ^ (row & 7);
                bf[nj] = *(const bf16x8*)(Bb + row * 128 + (ch << 4));
            }
#pragma unroll
            for (int mi = 0; mi < 4; ++mi)
#pragma unroll
                for (int nj = 0; nj < 4; ++nj)
                    acc[mi][nj] = __builtin_amdgcn_mfma_f32_16x16x32_bf16(
                        af[mi], bf[nj], acc[mi][nj], 0, 0, 0);
        }
        __builtin_amdgcn_s_barrier();          // all waves done reading buf[cur]
        __builtin_amdgcn_sched_barrier(0);
    }
#undef STAGE

    float*  C  = (float*)Cv + (size_t)blockIdx.z * zstride;
    ushort* Cb = (ushort*)Cv;
    ushort* C2 = (ushort*)Cv2;
#pragma unroll
    for (int mi = 0; mi < 4; ++mi) {
#pragma unroll
        for (int nj = 0; nj < 4; ++nj) {
            const int col  = bn + wc + (nj << 4) + lr;
            const int row0 = bm + wr + (mi << 4) + (lh << 2);
            if (col < N) {
#pragma unroll
                for (int r = 0; r < 4; ++r) {
                    const float v = acc[mi][nj][r];
                    if (epi == 0) {
                        C[(size_t)(row0 + r) * ldc + col] = v;
                    } else if (epi == 1) {
                        Cb[(size_t)(row0 + r) * ldc + col] =
                            (ushort)f2bf(softplusf_(v + bias[col]));
                    } else {  // epi == 5: dual bf16 store (fused in_proj)
                        if (col < D_INNER)
                            Cb[(size_t)(row0 + r) * ldc + col] = (ushort)f2bf(v);
                        else
                            C2[(size_t)(row0 + r) * ldc + (col - D_INNER)] = (ushort)f2bf(v);
                    }
                }
            }
        }
    }
}

// ---------------------------------------------------------------------------
__global__ __launch_bounds__(256)
void cvt_bf16(const float* __restrict__ in, ushort* __restrict__ out, int n8)
{
    for (int i = blockIdx.x * 256 + threadIdx.x; i < n8; i += gridDim.x * 256) {
        const float4 v0 = ((const float4*)in)[i * 2];
        const float4 v1 = ((const float4*)in)[i * 2 + 1];
        int4 p;
        p.x = (int)(f2bf(v0.x) | (f2bf(v0.y) << 16));
        p.y = (int)(f2bf(v0.z) | (f2bf(v0.w) << 16));
        p.z = (int)(f2bf(v1.x) | (f2bf(v1.y) << 16));
        p.w = (int)(f2bf(v1.z) | (f2bf(v1.w) << 16));
        ((int4*)out)[i] = p;
    }
}

// ---------------------------------------------------------------------------
__global__ __launch_bounds__(256)
void reduce_out(const float* __restrict__ part, float* __restrict__ out, int n4)
{
    for (int i = blockIdx.x * 256 + threadIdx.x; i < n4; i += gridDim.x * 256) {
        const float4 a = ((const float4*)part)[i];
        const float4 b = ((const float4*)(part + (size_t)M_TOK * D_MODEL))[i];
        ((float4*)out)[i] = make_float4(a.x + b.x, a.y + b.y, a.z + b.z, a.w + b.w);
    }
}

// ---------------------------------------------------------------------------
// Depthwise causal conv (K=4) + bias + SiLU. xraw bf16 [M][4096] -> xt bf16.
// ---------------------------------------------------------------------------
__global__ __launch_bounds__(256)
void conv_silu_k(const ushort* __restrict__ xraw,
                 const float* __restrict__ cw,
                 const float* __restrict__ cb,
                 ushort* __restrict__ xb)
{
    const int d = (blockIdx.x << 8) + threadIdx.x;
    const int m = blockIdx.y;
    const int l = m & (LSEQ - 1);
    const float4 w = *(const float4*)&cw[d << 2];
    const float wv[4] = {w.x, w.y, w.z, w.w};
    float acc = cb[d];
#pragma unroll
    for (int j = 0; j < 4; ++j) {
        const int ls = l - 3 + j;
        if (ls >= 0)
            acc = fmaf(wv[j], bf2f(xraw[(size_t)(m - 3 + j) * D_INNER + d]), acc);
    }
    const float sg = 1.f / (1.f + expf(-acc));
    xb[(size_t)m * D_INNER + d] = (ushort)f2bf(acc * sg);
}

// ---------------------------------------------------------------------------
__global__ __launch_bounds__(256)
void reduce_ssm(const float* __restrict__ part,
                float* __restrict__ ssmf, ushort* __restrict__ ssmb)
{
    const int i = blockIdx.x * 256 + threadIdx.x;   // < 2048*160
    float v = 0.f;
#pragma unroll
    for (int z = 0; z < 8; ++z) v += part[(size_t)z * (M_TOK * 160) + i];
    ssmf[i] = v;
    ssmb[i] = (ushort)f2bf(v);
}

// ---------------------------------------------------------------------------
// Chunked selective scan: thread owns (b, d, chunk), 16 states in VGPRs.
// ---------------------------------------------------------------------------
__global__ __launch_bounds__(256)
void scan_pass1(const ushort* __restrict__ dtp,   // dt bf16 [M][4096]
                const ushort* __restrict__ xb,    // x bf16 [M][4096]
                const float* __restrict__ ssm,    // [M][160], B @ 128+s
                const float* __restrict__ Ap,     // [4096][16]
                float* __restrict__ Pc, float* __restrict__ Qc)
{
    const int d = (blockIdx.x << 8) + threadIdx.x;
    const int c = blockIdx.y, b = blockIdx.z;
    float a[16];
    *(float4*)&a[0]  = *(const float4*)&Ap[d * 16];
    *(float4*)&a[4]  = *(const float4*)&Ap[d * 16 + 4];
    *(float4*)&a[8]  = *(const float4*)&Ap[d * 16 + 8];
    *(float4*)&a[12] = *(const float4*)&Ap[d * 16 + 12];
    float q[16];
#pragma unroll
    for (int s = 0; s < 16; ++s) q[s] = 0.f;
    float dtsum = 0.f;
    const size_t m0 = (size_t)b * LSEQ + (size_t)c * LCHUNK;
#pragma unroll 2
    for (int l = 0; l < LCHUNK; ++l) {
        const size_t m = m0 + l;
        const float dt = bf2f(dtp[m * D_INNER + d]);
        const float xv = bf2f(xb[m * D_INNER + d]);
        const float4 B0 = *(const float4*)&ssm[m * 160 + 128];
        const float4 B1 = *(const float4*)&ssm[m * 160 + 132];
        const float4 B2 = *(const float4*)&ssm[m * 160 + 136];
        const float4 B3 = *(const float4*)&ssm[m * 160 + 140];
        const float Bv[16] = {B0.x,B0.y,B0.z,B0.w, B1.x,B1.y,B1.z,B1.w,
                              B2.x,B2.y,B2.z,B2.w, B3.x,B3.y,B3.z,B3.w};
        const float t1 = dt * xv;
#pragma unroll
        for (int s = 0; s < 16; ++s) {
            const float dA = __expf(dt * a[s]);
            q[s] = fmaf(q[s], dA, t1 * Bv[s]);
        }
        dtsum += dt;
    }
    const size_t o = (((size_t)b * D_INNER + d) * NCHUNK + c) * D_STATE;
    float P[16];
#pragma unroll
    for (int s = 0; s < 16; ++s) P[s] = __expf(a[s] * dtsum);
#pragma unroll
    for (int s4 = 0; s4 < 4; ++s4) {
        *(float4*)&Pc[o + s4 * 4] = make_float4(P[s4*4], P[s4*4+1], P[s4*4+2], P[s4*4+3]);
        *(float4*)&Qc[o + s4 * 4] = make_float4(q[s4*4], q[s4*4+1], q[s4*4+2], q[s4*4+3]);
    }
}

__global__ __launch_bounds__(256)
void scan_pass2(const float* __restrict__ Pc, float* __restrict__ Qc)
{
    const int i = blockIdx.x * 256 + threadIdx.x;   // (b*4096+d)*16+s
    const size_t base = (size_t)(i >> 4) * (NCHUNK * D_STATE) + (i & 15);
    float st = 0.f;
#pragma unroll
    for (int c = 0; c < NCHUNK; ++c) {
        const float P = Pc[base + c * D_STATE];
        const float q = Qc[base + c * D_STATE];
        Qc[base + c * D_STATE] = st;    // state entering chunk c
        st = fmaf(st, P, q);
    }
}

__global__ __launch_bounds__(256)
void scan_pass3(const ushort* __restrict__ dtp,   // dt bf16
                ushort* __restrict__ xb,          // x bf16 in / y bf16 out
                const ushort* __restrict__ gb,    // gate bf16
                const float* __restrict__ ssm,
                const float* __restrict__ Ap,
                const float* __restrict__ Qc,
                const float* __restrict__ Dp)
{
    const int d = (blockIdx.x << 8) + threadIdx.x;
    const int c = blockIdx.y, b = blockIdx.z;
    float a[16], st[16];
    *(float4*)&a[0]  = *(const float4*)&Ap[d * 16];
    *(float4*)&a[4]  = *(const float4*)&Ap[d * 16 + 4];
    *(float4*)&a[8]  = *(const float4*)&Ap[d * 16 + 8];
    *(float4*)&a[12] = *(const float4*)&Ap[d * 16 + 12];
    const size_t qo = (((size_t)b * D_INNER + d) * NCHUNK + c) * D_STATE;
    *(float4*)&st[0]  = *(const float4*)&Qc[qo];
    *(float4*)&st[4]  = *(const float4*)&Qc[qo + 4];
    *(float4*)&st[8]  = *(const float4*)&Qc[qo + 8];
    *(float4*)&st[12] = *(const float4*)&Qc[qo + 12];
    const float Dd = Dp[d];
    const size_t m0 = (size_t)b * LSEQ + (size_t)c * LCHUNK;
#pragma unroll 2
    for (int l = 0; l < LCHUNK; ++l) {
        const size_t m = m0 + l;
        const float dt = bf2f(dtp[m * D_INNER + d]);
        const float xv = bf2f(xb[m * D_INNER + d]);
        const float gv = bf2f(gb[m * D_INNER + d]);
        const float4 B0 = *(const float4*)&ssm[m * 160 + 128];
        const float4 B1 = *(const float4*)&ssm[m * 160 + 132];
        const float4 B2 = *(const float4*)&ssm[m * 160 + 136];
        const float4 B3 = *(const float4*)&ssm[m * 160 + 140];
        const float4 C0 = *(const float4*)&ssm[m * 160 + 144];
        const float4 C1 = *(const float4*)&ssm[m * 160 + 148];
        const float4 C2 = *(const float4*)&ssm[m * 160 + 152];
        const float4 C3 = *(const float4*)&ssm[m * 160 + 156];
        const float Bv[16] = {B0.x,B0.y,B0.z,B0.w, B1.x,B1.y,B1.z,B1.w,
                              B2.x,B2.y,B2.z,B2.w, B3.x,B3.y,B3.z,B3.w};
        const float Cv[16] = {C0.x,C0.y,C0.z,C0.w, C1.x,C1.y,C1.z,C1.w,
                              C2.x,C2.y,C2.z,C2.w, C3.x,C3.y,C3.z,C3.w};
        const float t1 = dt * xv;
        float y = 0.f;
#pragma unroll
        for (int s = 0; s < 16; ++s) {
            const float dA = __expf(dt * a[s]);
            st[s] = fmaf(st[s], dA, t1 * Bv[s]);
            y = fmaf(st[s], Cv[s], y);
        }
        const float yg  = fmaf(Dd, xv, y);
        const float sig = 1.f / (1.f + expf(-gv));
        xb[m * D_INNER + d] = (ushort)f2bf(yg * (gv * sig));
    }
}

// ---------------------------------------------------------------------------
extern "C" void kernel_launch(void* const* d_in, const int* in_sizes, int n_in,
                              void* d_out, int out_size, void* d_ws, size_t ws_size,
                              hipStream_t stream)
{
    (void)in_sizes; (void)n_in; (void)out_size; (void)ws_size;
    const float* hs  = (const float*)d_in[0];  // [2048,2048]
    const float* inw = (const float*)d_in[1];  // [8192,2048]
    const float* cw  = (const float*)d_in[2];  // [4096,4]
    const float* cb  = (const float*)d_in[3];  // [4096]
    const float* xw  = (const float*)d_in[4];  // [160,4096]
    const float* dtw = (const float*)d_in[5];  // [4096,128]
    const float* dtb = (const float*)d_in[6];  // [4096]
    const float* Ap  = (const float*)d_in[7];  // [4096,16]
    const float* Dp  = (const float*)d_in[8];  // [4096]
    const float* ow  = (const float*)d_in[9];  // [2048,4096]
    float* out = (float*)d_out;                // [2048,2048]

    // ------------------------------------------------------------------
    // Workspace layout, f32-offset units. bf16 buffers list f32-EQUIV size
    // (= ushort_count/2). Total 24,150,016 f32 = 96.6 MB (< proven 105 MB).
    //   pg    [0,          4194304)  gate bf16 [2048][4096]      (4,194,304)
    //   xraw  [4194304,    8388608)  x bf16 pre-conv             (4,194,304)
    //   xtb   [8388608,   12582912)  xt bf16 -> y bf16           (4,194,304)
    //   ssmf  [12582912,  12910592)  f32 [2048][160]               (327,680)
    //   ssmb  [12910592,  13074432)  bf16 [2048][160]              (163,840)
    //   xwb   [13074432,  13402112)  bf16 [160][4096]              (327,680)
    //   dtwb  [13402112,  13664256)  bf16 [4096][128]              (262,144)
    //   hsb   [13664256,  15761408)  bf16 [2048][2048]           (2,097,152)
    //   inwb  [15761408,  24150016)  bf16 [8192][2048]           (8,388,608)
    // Aliases (single-writer-before-reader, verified on timeline):
    //   owb   = +15761408 bf16 [2048][4096] (4,194,304)  after in_proj
    //   part  = +19955712 f32 2,621,440                  x_proj, dead by dt_proj
    //   dtb16 = +19955712 bf16 [2048][4096] (4,194,304)  after reduce_ssm
    //   Pc    = +4194304  f32 2,097,152                  after conv (xraw dead)
    //   Qc    = +6291456  f32 2,097,152
    //   opart = +0        f32 2x4,194,304                after scan_pass3
    // ------------------------------------------------------------------
    float*  ws    = (float*)d_ws;
    ushort* pg    = (ushort*)(ws + 0);
    ushort* xraw  = (ushort*)(ws + 4194304);
    ushort* xtb   = (ushort*)(ws + 8388608);
    float*  ssmf  = ws + 12582912;
    ushort* ssmb  = (ushort*)(ws + 12910592);
    ushort* xwb   = (ushort*)(ws + 13074432);
    ushort* dtwb  = (ushort*)(ws + 13402112);
    ushort* hsb   = (ushort*)(ws + 13664256);
    ushort* inwb  = (ushort*)(ws + 15761408);
    ushort* owb   = (ushort*)(ws + 15761408);
    float*  part  = ws + 19955712;
    ushort* dtb16 = (ushort*)(ws + 19955712);
    float*  Pc    = ws + 4194304;
    float*  Qc    = ws + 6291456;
    float*  opart = ws + 0;

    const dim3 blk(256);

    // conversions
    cvt_bf16<<<dim3(1280), blk, 0, stream>>>(hs,  hsb,  524288);
    cvt_bf16<<<dim3(1280), blk, 0, stream>>>(inw, inwb, 2097152);
    cvt_bf16<<<dim3(1280), blk, 0, stream>>>(xw,  xwb,  81920);
    cvt_bf16<<<dim3(1280), blk, 0, stream>>>(dtw, dtwb, 65536);

    // in_proj (fused x+gate): [2048 x 8192] = hsb @ inwb^T, dual bf16 epilogue
    gemm_bf16_bt<<<dim3(64, 16, 1), blk, 0, stream>>>(
        hsb, D_MODEL, inwb, D_MODEL, xraw, D_INNER, pg, nullptr,
        M_TOK, 2 * D_INNER, D_MODEL, 5, 0);

    // ow conversion (inwb dead; owb = front of its region)
    cvt_bf16<<<dim3(1280), blk, 0, stream>>>(ow, owb, 1048576);

    // conv + SiLU: xraw -> xtb
    conv_silu_k<<<dim3(16, M_TOK), blk, 0, stream>>>(xraw, cw, cb, xtb);

    // x_proj split-K x8: part[z] = xtb @ xwb^T (K slice)
    gemm_bf16_bt<<<dim3(2, 16, 8), blk, 0, stream>>>(
        xtb, D_INNER, xwb, D_INNER, part, 160, nullptr, nullptr,
        M_TOK, 160, D_INNER, 0, (size_t)M_TOK * 160);
    reduce_ssm<<<dim3(1280), blk, 0, stream>>>(part, ssmf, ssmb);

    // dt_proj + softplus(+bias) -> dtb16 (bf16; part dead)
    gemm_bf16_bt<<<dim3(32, 16, 1), blk, 0, stream>>>(
        ssmb, 160, dtwb, DT_RANK, dtb16, D_INNER, nullptr, dtb,
        M_TOK, D_INNER, DT_RANK, 1, 0);

    // chunked selective scan (+ D-skip + gate), y bf16 over xtb
    scan_pass1<<<dim3(16, NCHUNK, B_SZ), blk, 0, stream>>>(dtb16, xtb, ssmf, Ap, Pc, Qc);
    scan_pass2<<<dim3((B_SZ * D_INNER * D_STATE) / 256), blk, 0, stream>>>(Pc, Qc);
    scan_pass3<<<dim3(16, NCHUNK, B_SZ), blk, 0, stream>>>(dtb16, xtb, pg, ssmf, Ap, Qc, Dp);

    // out_proj split-K x2: opart (pg+xraw region dead) -> reduce -> out
    gemm_bf16_bt<<<dim3(16, 16, 2), blk, 0, stream>>>(
        xtb, D_INNER, owb, D_INNER, opart, D_MODEL, nullptr, nullptr,
        M_TOK, D_MODEL, D_INNER, 0, (size_t)M_TOK * D_MODEL);
    reduce_out<<<dim3(1024), blk, 0, stream>>>(opart, out, (M_TOK * D_MODEL) / 4);
}